// Round 1
// baseline (130.846 us; speedup 1.0000x reference)
//
#include <hip/hip_runtime.h>
#include <math.h>

#define BB 8
#define PP 10
#define SS 160
#define FXD 11
#define DD 64
#define DFF 256
#define NROW (BB*PP*SS)   /* 12800 */
#define NBP  (BB*PP)      /* 80 */

// d_out layout (floats): pred | pred_resampl | K | V | R | attn
#define OFF_PRED  0
#define OFF_PREDR 12800
#define OFF_K     25600
#define OFF_V     844800
#define OFF_R     1664000
#define OFF_ATTN  2483200

typedef short short8 __attribute__((ext_vector_type(8)));
typedef float f32x4  __attribute__((ext_vector_type(4)));

__device__ __forceinline__ void fma4(float4& acc, float s, const float4& b){
  acc.x += s*b.x; acc.y += s*b.y; acc.z += s*b.z; acc.w += s*b.w;
}
template<int N>
__device__ __forceinline__ void wred_sum_n(float (&v)[N]){
#pragma unroll
  for (int m = 32; m >= 1; m >>= 1){
#pragma unroll
    for (int i = 0; i < N; ++i) v[i] += __shfl_xor(v[i], m, 64);
  }
}
// quad-local (16-lane) reductions
template<int N>
__device__ __forceinline__ void qred_sum_n(float (&v)[N]){
#pragma unroll
  for (int m = 8; m >= 1; m >>= 1){
#pragma unroll
    for (int i = 0; i < N; ++i) v[i] += __shfl_xor(v[i], m, 64);
  }
}
template<int N>
__device__ __forceinline__ void qred_max_n(float (&v)[N]){
#pragma unroll
  for (int m = 8; m >= 1; m >>= 1){
#pragma unroll
    for (int i = 0; i < N; ++i) v[i] = fmaxf(v[i], __shfl_xor(v[i], m, 64));
  }
}
// bf16 pack (RTN-even)
__device__ __forceinline__ unsigned f2bf(float f){
  unsigned u = __float_as_uint(f);
  return (u + 0x7fffu + ((u >> 16) & 1u)) >> 16;
}
__device__ __forceinline__ unsigned packbf2(float x, float y){
  return f2bf(x) | (f2bf(y) << 16);
}
__device__ __forceinline__ f32x4 mfma16(uint4 a, uint4 b, f32x4 c){
  union { uint4 u; short8 s; } ua, ub;
  ua.u = a; ub.u = b;
  return __builtin_amdgcn_mfma_f32_16x16x32_bf16(ua.s, ub.s, c, 0, 0, 0);
}
__device__ __forceinline__ uint4 pack8(float4 a, float4 b){
  uint4 r;
  r.x = packbf2(a.x, a.y); r.y = packbf2(a.z, a.w);
  r.z = packbf2(b.x, b.y); r.w = packbf2(b.z, b.w);
  return r;
}

// ---------------------------------------------------------------------------
// proj (fp32) + QKV via MFMA (B-frags in-register from global fp32).
// Emits: x (fp32), Kc/Vc (fp32 outputs), Qp/Kp (bf16 packed along d,
// [row][32]u32 = A/B frag layout), Vp (bf16 packed along s, [bp][d][80]u32 =
// V^T B-frag layout). Blocks 0..71 also pack Wo/W1/W2 into wpack.
// QKV weight frags are hoisted above the barriers so their global-load
// latency hides under input staging / x-projection.
// ---------------------------------------------------------------------------
__global__ __launch_bounds__(256) void k_xqkv(const float* __restrict__ inp,
    const float* __restrict__ Wp, const float* __restrict__ bpj,
    const float* __restrict__ Wq, const float* __restrict__ bq,
    const float* __restrict__ Wk, const float* __restrict__ bk,
    const float* __restrict__ Wv, const float* __restrict__ bv,
    const float* __restrict__ Wo, const float* __restrict__ W1,
    const float* __restrict__ W2, unsigned* __restrict__ wpack,
    float* __restrict__ x, unsigned* __restrict__ Qp,
    unsigned* __restrict__ Kp, unsigned* __restrict__ Vp,
    float* __restrict__ Kc, float* __restrict__ Vc){
  __shared__ __align__(16) float ins[16*12];
  __shared__ __align__(16) unsigned xs2[16*36];
  int tid = threadIdx.x;
  int g = blockIdx.x;
  int row0 = g*16;
  int lane = tid & 63, w = tid >> 6, nl = lane & 15, q = lane >> 4;
  int n = w*16 + nl;
  // ---- hoisted QKV weight frag loads + bf16 packs (no barrier deps) ----
  uint4 wb[3][2];
  float bias3[3];
  {
    const float* Wm[3] = {Wq, Wk, Wv};
#pragma unroll
    for (int mat = 0; mat < 3; ++mat){
      const float* W = Wm[mat];
#pragma unroll
      for (int h = 0; h < 2; ++h){
        int kb = h*32;
        float w0 = W[(kb+q*8+0)*64+n], w1 = W[(kb+q*8+1)*64+n];
        float w2 = W[(kb+q*8+2)*64+n], w3 = W[(kb+q*8+3)*64+n];
        float w4 = W[(kb+q*8+4)*64+n], w5 = W[(kb+q*8+5)*64+n];
        float w6 = W[(kb+q*8+6)*64+n], w7 = W[(kb+q*8+7)*64+n];
        wb[mat][h].x = packbf2(w0,w1); wb[mat][h].y = packbf2(w2,w3);
        wb[mat][h].z = packbf2(w4,w5); wb[mat][h].w = packbf2(w6,w7);
      }
    }
    bias3[0] = bq[n]; bias3[1] = bk[n]; bias3[2] = bv[n];
  }
  // ---- weight pack for k_attn_ffn (blocks 0..71) ----
  {
    int pi = g*256 + tid;
    if (pi < 18432){
      const float* W; int N, K2, base, off;
      if (pi < 2048){ W = Wo; N = 64; K2 = 32; base = 0; off = pi; }
      else if (pi < 10240){ W = W1; N = 256; K2 = 32; base = 2048; off = pi - 2048; }
      else { W = W2; N = 64; K2 = 128; base = 10240; off = pi - 10240; }
      int nn = off % N, k2 = off / N;
      wpack[base + nn*K2 + k2] = packbf2(W[(2*k2)*N + nn], W[(2*k2+1)*N + nn]);
    }
  }
  // ---- stage inputs ----
  for (int i = tid; i < 16*FXD; i += 256){
    int r = i / FXD, f = i - r*FXD;
    ins[r*12 + f] = inp[row0*FXD + i];
  }
  __syncthreads();
  int tc = tid & 15, tr = tid >> 4;
  // ---- x = (inp @ Wp + bp) * 8 ----
  {
    float4 a = make_float4(0.f,0.f,0.f,0.f);
#pragma unroll
    for (int f = 0; f < FXD; ++f){
      float v = ins[tr*12 + f];
      float4 w4 = *(const float4*)&Wp[f*64 + tc*4];
      fma4(a, v, w4);
    }
    float4 bp4 = *(const float4*)&bpj[tc*4];
    float4 xv = make_float4((a.x+bp4.x)*8.f, (a.y+bp4.y)*8.f,
                            (a.z+bp4.z)*8.f, (a.w+bp4.w)*8.f);
    *(float4*)&x[(row0+tr)*64 + tc*4] = xv;
    xs2[tr*36 + tc*2]     = packbf2(xv.x, xv.y);
    xs2[tr*36 + tc*2 + 1] = packbf2(xv.z, xv.w);
  }
  __syncthreads();
  uint4 a0 = *(const uint4*)&xs2[nl*36 + q*4];
  uint4 a1 = *(const uint4*)&xs2[nl*36 + 16 + q*4];
  bool evenlane = !(lane & 1);
  int bpg = g / 10, loc0 = (g - bpg*10)*16;     // bp, local t base
#pragma unroll
  for (int mat = 0; mat < 3; ++mat){
    f32x4 acc = {0.f,0.f,0.f,0.f};
    acc = mfma16(a0, wb[mat][0], acc);
    acc = mfma16(a1, wb[mat][1], acc);
    float bvv = bias3[mat];
    float o[4];
#pragma unroll
    for (int r = 0; r < 4; ++r) o[r] = acc[r] + bvv;
    if (mat == 0){
      // Qp packed along d
#pragma unroll
      for (int r = 0; r < 4; ++r){
        float on = __shfl_xor(o[r], 1, 64);
        if (evenlane) Qp[(row0 + q*4 + r)*32 + (n >> 1)] = packbf2(o[r], on);
      }
    } else if (mat == 1){
#pragma unroll
      for (int r = 0; r < 4; ++r){
        Kc[(row0 + q*4 + r)*64 + n] = o[r];
        float on = __shfl_xor(o[r], 1, 64);
        if (evenlane) Kp[(row0 + q*4 + r)*32 + (n >> 1)] = packbf2(o[r], on);
      }
    } else {
#pragma unroll
      for (int r = 0; r < 4; ++r)
        Vc[(row0 + q*4 + r)*64 + n] = o[r];
      // Vp packed along s (pairs of rows live in this thread)
      unsigned* vd = &Vp[bpg*(64*80) + n*80 + (loc0 >> 1) + q*2];
      vd[0] = packbf2(o[0], o[1]);
      vd[1] = packbf2(o[2], o[3]);
    }
  }
}

// ---------------------------------------------------------------------------
// Mega-fused attention+FFN, all matmuls MFMA. 16 t-rows/block, grid (10,80)
// with c = blockIdx.x fastest so heavy/light causal tiles interleave in
// dispatch order (tail balance). Only live causal tiles computed (tiles
// 0..c); dead attn columns zero-filled with float4 stores. Q/K/V read
// pre-packed (Qp/Kp/Vp). Phase-B V frags, phase-C Wo frags + x residual are
// prefetched at kernel entry: the vmcnt(0) drain at the first barrier means
// their latency hides under phase A instead of stalling phases B/C.
// LDS ~30KB, 4 blk/CU.
// ---------------------------------------------------------------------------
__global__ __launch_bounds__(256, 4) void k_attn_ffn(
    const unsigned* __restrict__ Qp, const unsigned* __restrict__ Kp,
    const unsigned* __restrict__ Vp, const unsigned* __restrict__ wpack,
    const float* __restrict__ bo,
    const float* __restrict__ g1, const float* __restrict__ b1l,
    const float* __restrict__ x,
    const float* __restrict__ b1, const float* __restrict__ b2,
    const float* __restrict__ g2, const float* __restrict__ b2l,
    const float* __restrict__ Wf, const float* __restrict__ bf,
    float* __restrict__ attn, float* __restrict__ R,
    float* __restrict__ pred, float* __restrict__ predr){
  __shared__ __align__(16) unsigned char smA[5376];   // ps2 -> zos (overlay)
  unsigned* ps2 = (unsigned*)smA;                     // 16 x 84 u32
  float*    zos = (float*)smA;                        // 16 x 68 f
  __shared__ float mws[80], sws[80];
  __shared__ __align__(16) float zs[16*68];
  __shared__ __align__(16) float os[16*68];
  __shared__ __align__(16) unsigned os2[16*36];
  __shared__ __align__(16) unsigned as2[16*132];
  __shared__ __align__(16) float lnb[16*68];

  int tid = threadIdx.x;
  int c = blockIdx.x, bp = blockIdx.y;      // c fastest -> balanced dispatch
  int t0 = c*16;
  float* Ab = attn + bp*(SS*SS);
  const unsigned* wop = wpack;
  const unsigned* w1p = wpack + 2048;
  const unsigned* w2p = wpack + 10240;

  int lane = tid & 63, w = tid >> 6, nl = lane & 15, q = lane >> 4;
  int dcol = w*16 + nl;

  // ---- early prefetch (latency hides under phase A; drained at barrier) ----
  uint4 vpre[5];
  {
    const unsigned* vpd = &Vp[bp*(64*80) + dcol*80];
#pragma unroll
    for (int ks = 0; ks < 5; ++ks)
      vpre[ks] = *(const uint4*)&vpd[ks*16 + q*4];
  }
  uint4 wo_pre[2];
#pragma unroll
  for (int ks = 0; ks < 2; ++ks)
    wo_pre[ks] = *(const uint4*)&wop[dcol*32 + ks*16 + q*4];
  float xr[4];
#pragma unroll
  for (int r = 0; r < 4; ++r)
    xr[r] = x[(bp*SS + t0 + q*4 + r)*64 + dcol];
  float bov = bo[dcol];

  // ---- zero-fill dead attn columns (tiles > c): s in [(c+1)*16, 160) ----
  {
    int zc0 = (c+1)*16;
    int zcw = 160 - zc0;                    // multiple of 16 (0 when c=9)
    int nq = (16*zcw) >> 2;                 // float4 count
    int perrow = zcw >> 2;
    for (int i = tid; i < nq; i += 256){
      int r = i / perrow, col = zc0 + (i - r*perrow)*4;
      *(float4*)&Ab[(t0 + r)*SS + col] = make_float4(0.f,0.f,0.f,0.f);
    }
    // zero the ps2 pad tile when phase-B K-step overshoots ((c+1) odd <=> c even)
    if (!(c & 1) && tid < 128){
      int r = tid >> 3, j = tid & 7;
      ps2[r*84 + (c+1)*8 + j] = 0;
    }
  }

  // ---- phase A: logits via MFMA over live tiles only ----
  int ntiles = (w <= c) ? (((c - w) >> 2) + 1) : 0;   // wave w: tiles w,w+4,w+8 <= c
  {
    const unsigned* qpr = &Qp[(bp*SS + t0 + nl)*32];
    uint4 aq0 = *(const uint4*)&qpr[q*4];
    uint4 aq1 = *(const uint4*)&qpr[16 + q*4];
    float lg[3][4], ev[3][4];
    f32x4 pacc[3];
#pragma unroll
    for (int i = 0; i < 3; ++i){
      pacc[i] = (f32x4){0.f,0.f,0.f,0.f};
      if (i < ntiles){
        const unsigned* kpr = &Kp[(bp*SS + (w+4*i)*16 + nl)*32];
        uint4 b0 = *(const uint4*)&kpr[q*4];
        uint4 b1 = *(const uint4*)&kpr[16 + q*4];
        pacc[i] = mfma16(aq0, b0, pacc[i]);
        pacc[i] = mfma16(aq1, b1, pacc[i]);
      }
    }
    float mw_[4];
#pragma unroll
    for (int r = 0; r < 4; ++r){
      int t = t0 + q*4 + r;
      float m_ = -1e30f;
#pragma unroll
      for (int i = 0; i < 3; ++i){
        if (i < ntiles){
          int s = (w + 4*i)*16 + nl;
          float l = (s <= t) ? pacc[i][r]*0.125f : -1e30f;
          lg[i][r] = l; m_ = fmaxf(m_, l);
        }
      }
      mw_[r] = m_;
    }
    qred_max_n<4>(mw_);
    float sw_[4];
#pragma unroll
    for (int r = 0; r < 4; ++r){
      float s_ = 0.f;
#pragma unroll
      for (int i = 0; i < 3; ++i){
        if (i < ntiles){
          float e = __expf(lg[i][r] - mw_[r]);
          ev[i][r] = e; s_ += e;
        }
      }
      sw_[r] = s_;
    }
    qred_sum_n<4>(sw_);
    if (nl == 0){
#pragma unroll
      for (int r = 0; r < 4; ++r){
        mws[(q*4+r)*5 + w] = mw_[r];
        sws[(q*4+r)*5 + w] = sw_[r];
      }
    }
    __syncthreads();
    float scale[4];
#pragma unroll
    for (int r = 0; r < 4; ++r){
      int row = q*4 + r;
      float m0 = mws[row*5+0], m1 = mws[row*5+1];
      float m2 = mws[row*5+2], m3 = mws[row*5+3];
      float gm = fmaxf(fmaxf(m0,m1), fmaxf(m2,m3));
      float tot = sws[row*5+0]*__expf(m0-gm) + sws[row*5+1]*__expf(m1-gm)
                + sws[row*5+2]*__expf(m2-gm) + sws[row*5+3]*__expf(m3-gm);
      scale[r] = __expf(mw_[r]-gm) / tot;
    }
#pragma unroll
    for (int i = 0; i < 3; ++i){
      if (i < ntiles){
        int s = (w + 4*i)*16 + nl;
#pragma unroll
        for (int r = 0; r < 4; ++r){
          float p_ = ev[i][r] * scale[r];
          Ab[(t0 + q*4 + r)*SS + s] = p_;
          float pn = __shfl_xor(p_, 1, 64);
          if (!(nl & 1))
            ps2[(q*4+r)*84 + (w+4*i)*8 + (nl >> 1)] = packbf2(p_, pn);
        }
      }
    }
  }
  __syncthreads();

  // ---- phase B: Z = P @ V over live K-range; V frags prefetched ----
  {
    int nks = (c + 2) >> 1;                 // 32-wide K steps needed
    f32x4 zacc = {0.f,0.f,0.f,0.f};
#pragma unroll
    for (int ks = 0; ks < 5; ++ks){
      if (ks < nks){
        uint4 ap = *(const uint4*)&ps2[nl*84 + ks*16 + q*4];
        zacc = mfma16(ap, vpre[ks], zacc);
      }
    }
#pragma unroll
    for (int r = 0; r < 4; ++r)
      zs[(q*4+r)*68 + dcol] = zacc[r];
  }
  __syncthreads();

  // ---- phase C: zo = Z@Wo + bo + x (zos overlays ps2 region) ----
  {
    f32x4 cacc = {0.f,0.f,0.f,0.f};
#pragma unroll
    for (int ks = 0; ks < 2; ++ks){
      float4 f0 = *(const float4*)&zs[nl*68 + ks*32 + q*8];
      float4 f1 = *(const float4*)&zs[nl*68 + ks*32 + q*8 + 4];
      uint4 a = pack8(f0, f1);
      cacc = mfma16(a, wo_pre[ks], cacc);
    }
#pragma unroll
    for (int r = 0; r < 4; ++r){
      int row = q*4 + r;
      zos[row*68 + dcol] = cacc[r] + bov + xr[r];
    }
  }
  __syncthreads();

  // ---- LN1 -> os (fp32) + os2 (packed bf16) ----
  {
    float h[4], s8v[8];
#pragma unroll
    for (int j = 0; j < 4; ++j){
      int r = w + 4*j;
      h[j] = zos[r*68 + lane];
      s8v[j] = h[j]; s8v[4+j] = h[j]*h[j];
    }
    wred_sum_n<8>(s8v);
    float gl = g1[lane], bl = b1l[lane];
#pragma unroll
    for (int j = 0; j < 4; ++j){
      int r = w + 4*j;
      float mu = s8v[j]*(1.f/64.f);
      float var = s8v[4+j]*(1.f/64.f) - mu*mu;
      float o = gl*(h[j]-mu)*rsqrtf(fmaxf(var,0.f) + 1e-6f) + bl;
      os[r*68 + lane] = o;
      float on = __shfl_xor(o, 1, 64);
      if (!(lane & 1)) os2[r*36 + (lane >> 1)] = packbf2(o, on);
    }
  }
  __syncthreads();

  // ---- FFN1: a = relu(os@W1+b1); wave w -> n-tiles w*4..w*4+3 ----
  {
    uint4 ao0 = *(const uint4*)&os2[nl*36 + q*4];
    uint4 ao1 = *(const uint4*)&os2[nl*36 + 16 + q*4];
    f32x4 fa[4];
#pragma unroll
    for (int i = 0; i < 4; ++i){
      fa[i] = (f32x4){0.f,0.f,0.f,0.f};
      int n = (w*4+i)*16 + nl;
      uint4 b0 = *(const uint4*)&w1p[n*32 + q*4];
      uint4 b1v = *(const uint4*)&w1p[n*32 + 16 + q*4];
      fa[i] = mfma16(ao0, b0, fa[i]);
      fa[i] = mfma16(ao1, b1v, fa[i]);
    }
#pragma unroll
    for (int i = 0; i < 4; ++i){
      int n = (w*4+i)*16 + nl;
      float b1b = b1[n];
#pragma unroll
      for (int r = 0; r < 4; ++r){
        float a_ = fmaxf(fa[i][r] + b1b, 0.f);
        float an = __shfl_xor(a_, 1, 64);
        if (!(nl & 1))
          as2[(q*4+r)*132 + w*32 + i*8 + (nl >> 1)] = packbf2(a_, an);
      }
    }
  }
  __syncthreads();

  // ---- FFN2: r0 = a@W2 + b2 + os ----
  {
    f32x4 f2 = {0.f,0.f,0.f,0.f};
#pragma unroll
    for (int ks = 0; ks < 8; ++ks){
      uint4 a = *(const uint4*)&as2[nl*132 + ks*16 + q*4];
      uint4 b = *(const uint4*)&w2p[(w*16+nl)*128 + ks*16 + q*4];
      f2 = mfma16(a, b, f2);
    }
    float b2v = b2[dcol];
#pragma unroll
    for (int r = 0; r < 4; ++r){
      int row = q*4 + r;
      lnb[row*68 + dcol] = f2[r] + b2v + os[row*68 + dcol];
    }
  }
  __syncthreads();

  // ---- LN2 -> R, pred ----
  {
    float wfv = Wf[lane], bfv = bf[0];
    float h[4], s8v[8];
#pragma unroll
    for (int j = 0; j < 4; ++j){
      int r = w*4 + j;
      h[j] = lnb[r*68 + lane];
      s8v[j] = h[j]; s8v[4+j] = h[j]*h[j];
    }
    wred_sum_n<8>(s8v);
    float g2l = g2[lane], b2ll = b2l[lane];
    float pr[4];
#pragma unroll
    for (int j = 0; j < 4; ++j){
      int r = w*4 + j;
      float mu = s8v[j]*(1.f/64.f);
      float var = s8v[4+j]*(1.f/64.f) - mu*mu;
      float rv = g2l*(h[j]-mu)*rsqrtf(fmaxf(var,0.f) + 1e-6f) + b2ll;
      int grow = bp*SS + t0 + r;
      R[grow*64 + lane] = rv;
      pr[j] = rv * wfv;
    }
    wred_sum_n<4>(pr);
    if (lane == 0){
#pragma unroll
      for (int j = 0; j < 4; ++j){
        int grow = bp*SS + t0 + w*4 + j;
        pred[grow]  = pr[j] + bfv;
        predr[grow] = pr[j] + bfv;
      }
    }
  }
}

extern "C" void kernel_launch(void* const* d_in, const int* in_sizes, int n_in,
                              void* d_out, int out_size, void* d_ws, size_t ws_size,
                              hipStream_t stream){
  const float* inputs = (const float*)d_in[0];
  const float* Wp  = (const float*)d_in[2];
  const float* bpj = (const float*)d_in[3];
  const float* Wq  = (const float*)d_in[4];  const float* bq  = (const float*)d_in[5];
  const float* Wk  = (const float*)d_in[6];  const float* bk  = (const float*)d_in[7];
  const float* Wv  = (const float*)d_in[8];  const float* bv  = (const float*)d_in[9];
  const float* Wo  = (const float*)d_in[10]; const float* bo  = (const float*)d_in[11];
  const float* g1  = (const float*)d_in[12]; const float* b1l = (const float*)d_in[13];
  const float* W1  = (const float*)d_in[14]; const float* b1  = (const float*)d_in[15];
  const float* W2  = (const float*)d_in[16]; const float* b2  = (const float*)d_in[17];
  const float* g2  = (const float*)d_in[18]; const float* b2l = (const float*)d_in[19];
  const float* Wf  = (const float*)d_in[20]; const float* bf  = (const float*)d_in[21];

  float* outp = (float*)d_out;
  float* ws   = (float*)d_ws;
  float* x    = ws;                               // 819200 floats
  unsigned* Qp = (unsigned*)(ws + 819200);        // 409600 u32
  unsigned* Kp = Qp + 409600;                     // 409600 u32
  unsigned* Vp = Kp + 409600;                     // 409600 u32
  unsigned* wpack = Vp + 409600;                  // 18432 u32

  float* pred  = outp + OFF_PRED;
  float* predr = outp + OFF_PREDR;
  float* Kc    = outp + OFF_K;
  float* Vc    = outp + OFF_V;
  float* Rr    = outp + OFF_R;
  float* attn  = outp + OFF_ATTN;

  k_xqkv<<<NROW/16, 256, 0, stream>>>(inputs, Wp, bpj, Wq, bq, Wk, bk, Wv, bv,
                                      Wo, W1, W2, wpack, x, Qp, Kp, Vp, Kc, Vc);
  k_attn_ffn<<<dim3(10, NBP), 256, 0, stream>>>(Qp, Kp, Vp, wpack,
                                                bo, g1, b1l, x, b1, b2,
                                                g2, b2l, Wf, bf,
                                                attn, Rr, pred, predr);
}